// Round 1
// baseline (278.509 us; speedup 1.0000x reference)
//
#include <hip/hip_runtime.h>

// Problem: B=32,T=12,N=325,D=64,H=4,HD=16,M_SP=32,M_T=6, SCALE=0.25
// Inputs fp32 (+ int32 mode lists); output fp32.
//
// Key identities used:
//  * temporal branch: softmax axis == mean axis  =>  out = vf/6. Whole branch is
//    v=x@Wv_t^T (fake (n',t') reshape r = n'*12+t'), drop Nyquist of 12-pt rfft, /6.
//  * rfft over n commutes with channel linear => one DFT of x, then 64x64 matmuls.
//  * norms: ||q||^2 computed directly as sum q^2 fused into k_linear2's MFMA pass.
//  * GCN: Wc = W_mlp @ W_fc1 folded; out = A_rownorm @ (x @ Wc^T) + b.
//
// R8 (this round): latency-bound fixes.
//  - k_prep precomputes bf16 fragment-ready weights: WBB ([Wc|Wvt|Wq|Wk], 256x64)
//    and WSPB ([Wq|Wk|Wv], 192x64), aliased into the ALT region (dead until k_alt).
//  - k_linear2: 512 threads / 8 waves, acc[16]/wave; B-fragments straight from
//    global WBB (no 36KB LDS stage, no per-block weight f2bf); LDS = XA only
//    (18.4KB), XA reused for the xcT transpose. Occupancy 2 -> 3+ waves/SIMD.
//  - k_spatial3: phase-A A-frags direct from global TB, x-tile double-buffered
//    (1 barrier/chunk); phase-B W-frags direct from global WSPB.
//  - k_final2: barrier-free, zero LDS: all operands are bf16 fragment-ready in ws.
//  - XCT pad-zeroing moved into k_prep (was a 17MB memset for 1.3MB of pads).

typedef unsigned short u16;
typedef short short8 __attribute__((ext_vector_type(8)));
typedef float floatx4 __attribute__((ext_vector_type(4)));

__device__ __forceinline__ u16 f2bf(float f) {
  union { float fp; unsigned int u; } v; v.fp = f;
  unsigned int x = v.u;
  x += 0x7FFF + ((x >> 16) & 1);   // RNE
  return (u16)(x >> 16);
}

// ---- workspace layout (float offsets; u16 arrays count as size/2 floats) ----
constexpr size_t OFF_NORM = 4096;       // 2       [0]=sum q^2, [1]=sum k^2 (memset 0)
constexpr size_t OFF_WQA  = 8208;       // 15872   |weights_Q|
constexpr size_t OFF_ANB  = 24080;      // u16[325*352]   row-norm adj, bf16, col-pad 352
constexpr size_t OFF_TB   = 81280;      // u16[64*352]    DFT matrix bf16, rows interleaved re/im
constexpr size_t OFF_T2   = 102080;     // u16[325*64]    irfft: [n][2j]=wc_j cos, [n][2j+1]=-wc_j sin
constexpr size_t OFF_OFT  = 112480;     // u16[384*64*64] spectrum [bt][d][2j|2j+1] (re,im)
constexpr size_t OFF_XCT  = 898912;     // u16[384*64*352] xc transposed [bt][d][n], n-pad 352
constexpr size_t OFF_VT   = 5224288;    // f32[124800*64]  x @ Wv_t^T
constexpr size_t OFF_ALT  = 13211488;   // f32[665600]     alternating sums
// bf16 weight tables alias ALT: written by k_prep, last read by k_spatial3,
// overwritten by k_alt (which runs after k_spatial3).
constexpr size_t OFF_WBB  = OFF_ALT;          // u16[256*64]  [Wc|Wvt|Wq|Wk]
constexpr size_t OFF_WSPB = OFF_ALT + 8192;   // u16[192*64]  [Wq|Wk|Wv]

// ===========  K2: WBB/WSPB, |wQ|, adj row-norm (bf16), twiddles, XCT pads  ===========
__global__ __launch_bounds__(256) void k_prep(const float* __restrict__ adj,
                                              const float* __restrict__ Wmlp,
                                              const float* __restrict__ Wfc1,
                                              const float* __restrict__ wQ,
                                              const float* __restrict__ Wvt,
                                              const float* __restrict__ Wq,
                                              const float* __restrict__ Wk,
                                              const float* __restrict__ Wv,
                                              const int* __restrict__ sp_modes,
                                              float* __restrict__ ws) {
  __shared__ float red[256];
  const int tid = threadIdx.x;
  const int blk = blockIdx.x;
  u16* WBBu = (u16*)(ws + OFF_WBB);
  if (blk == 0) {
    // Wc = Wmlp @ Wfc1, straight to bf16 rows 0..63 of WBB
    for (int o = tid; o < 4096; o += 256) {
      int g = o >> 6, dd = o & 63;
      float s = 0.f;
      for (int e = 0; e < 64; ++e)
        s = fmaf(Wmlp[g * 64 + e], Wfc1[e * 64 + dd], s);
      WBBu[o] = f2bf(s);
    }
  } else if (blk < 9) {
    for (int i = (blk - 1) * 256 + tid; i < 15872; i += 2048)
      ws[OFF_WQA + i] = fabsf(wQ[i]);
  } else if (blk < 334) {
    const int n = blk - 9;
    float p = 0.f;
    for (int k = tid; k < 325; k += 256) p += adj[n * 325 + k];
    red[tid] = p;
    __syncthreads();
    for (int s2 = 128; s2 > 0; s2 >>= 1) {
      if (tid < s2) red[tid] += red[tid + s2];
      __syncthreads();
    }
    const float inv = 1.f / red[0];
    u16* ANB = (u16*)(ws + OFF_ANB);
    for (int k = tid; k < 352; k += 256)
      ANB[(size_t)n * 352 + k] = (k < 325) ? f2bf(adj[n * 325 + k] * inv) : (u16)0;
  } else if (blk < 366) {
    const int j = blk - 334;  // < 32
    const int f = sp_modes[j];
    const float wgt = (f == 0) ? 1.f : 2.f;
    u16* T2B = (u16*)(ws + OFF_T2);
    u16* TB = (u16*)(ws + OFF_TB);
    // interleaved row order: rows 8g+0..3 = re f(4g..4g+3); 8g+4..7 = im
    const int row_re = 8 * (j >> 2) + (j & 3);
    const int row_im = row_re + 4;
    for (int n = tid; n < 352; n += 256) {
      float c = 0.f, s = 0.f;
      if (n < 325) {
        int mm = (f * n) % 325;               // exact range reduction
        float th = 6.283185307179586f * (float)mm * (1.f / 325.f);
        c = cosf(th);
        s = sinf(th);
      }
      TB[(size_t)row_re * 352 + n] = f2bf(c);
      TB[(size_t)row_im * 352 + n] = f2bf(-s);
      if (n < 325) {
        T2B[(size_t)n * 64 + 2 * j] = f2bf(wgt * (1.f / 325.f) * c);
        T2B[(size_t)n * 64 + 2 * j + 1] = f2bf(-wgt * (1.f / 325.f) * s);
      }
    }
  } else if (blk == 366) {
    // WBB rows 64..255: Wvt | Wq | Wk
    for (int i = tid; i < 12288; i += 256) {
      const int r = i >> 6, e = i & 63;
      const float* src = (r < 64) ? Wvt : (r < 128) ? Wq : Wk;
      WBBu[4096 + i] = f2bf(src[(size_t)(r & 63) * 64 + e]);
    }
  } else if (blk == 367) {
    u16* WSPBu = (u16*)(ws + OFF_WSPB);
    for (int i = tid; i < 12288; i += 256) {
      const int r = i >> 6, e = i & 63;
      const float* src = (r < 64) ? Wq : (r < 128) ? Wk : Wv;
      WSPBu[i] = f2bf(src[(size_t)(r & 63) * 64 + e]);
    }
  } else {
    // zero XCT n-pads [bt][d][325..352)
    const int idx = (blk - 368) * 256 + tid;   // < 24576 = 384*64
    u16* p = (u16*)(ws + OFF_XCT) + (size_t)(idx >> 6) * 22528 + (size_t)(idx & 63) * 352;
    for (int c = 325; c < 352; ++c) p[c] = 0;
  }
}

// =======  K4 (R8): one MFMA pass over x: xc->XCT, vt->VT, ||q||^2/||k||^2  =======
// 975 blocks x 128 rows x 512 threads (8 waves, 16 rows/wave, acc[16]).
// A = x[128][64] bf16 in LDS (stride 72). B = WBB (global bf16, fragment-ready).
__global__ __launch_bounds__(512, 3) void k_linear2(const float* __restrict__ x,
                                                    float* __restrict__ ws) {
  __shared__ __align__(16) u16 XA[128 * 72];   // 18432 B; reused as xcT[64][132]
  __shared__ float reds[16];
  const int tid = threadIdx.x;
  const int wv = tid >> 6, lane = tid & 63, lc = lane & 15, quad = lane >> 4;
  const size_t base = (size_t)blockIdx.x * 128;
  const u16* WBBu = (const u16*)(ws + OFF_WBB);

  for (int i = tid; i < 2048; i += 512) {
    const int row = i >> 4, e0 = (i & 15) * 4;
    const float4 v = *(const float4*)(x + (base + row) * 64 + e0);
    u16* dst = &XA[row * 72 + e0];
    dst[0] = f2bf(v.x); dst[1] = f2bf(v.y); dst[2] = f2bf(v.z); dst[3] = f2bf(v.w);
  }
  __syncthreads();

  floatx4 acc[16] = {};
#pragma unroll
  for (int kc = 0; kc < 2; ++kc) {
    const short8 af = *(const short8*)&XA[(16 * wv + lc) * 72 + kc * 32 + quad * 8];
#pragma unroll
    for (int ni = 0; ni < 16; ++ni) {
      const short8 bf_ = *(const short8*)&WBBu[(ni * 16 + lc) * 64 + kc * 32 + quad * 8];
      acc[ni] = __builtin_amdgcn_mfma_f32_16x16x32_bf16(af, bf_, acc[ni], 0, 0, 0);
    }
  }

  // VT (f32) + q/k squared partial sums
  float sq = 0.f, sk = 0.f;
#pragma unroll
  for (int reg = 0; reg < 4; ++reg) {
    const int row = 16 * wv + quad * 4 + reg;
#pragma unroll
    for (int ni = 0; ni < 4; ++ni)
      ws[OFF_VT + (base + row) * 64 + ni * 16 + lc] = acc[4 + ni][reg];
#pragma unroll
    for (int ni = 0; ni < 4; ++ni) {
      const float v = acc[8 + ni][reg];
      sq = fmaf(v, v, sq);
    }
#pragma unroll
    for (int ni = 0; ni < 4; ++ni) {
      const float v = acc[12 + ni][reg];
      sk = fmaf(v, v, sk);
    }
  }
  for (int off = 32; off > 0; off >>= 1) {
    sq += __shfl_down(sq, off);
    sk += __shfl_down(sk, off);
  }
  if (lane == 0) { reds[wv] = sq; reds[8 + wv] = sk; }
  __syncthreads();   // also: all af reads of XA complete past this point
  if (tid == 0)
    atomicAdd(&ws[OFF_NORM + 0], reds[0] + reds[1] + reds[2] + reds[3] +
                                 reds[4] + reds[5] + reds[6] + reds[7]);
  if (tid == 1)
    atomicAdd(&ws[OFF_NORM + 1], reds[8] + reds[9] + reds[10] + reds[11] +
                                 reds[12] + reds[13] + reds[14] + reds[15]);

  // xc -> xcT[64 d][132] bf16 reusing XA (stride 132: 66 dw = +2 banks/lane)
  u16* xcT = XA;
#pragma unroll
  for (int ni = 0; ni < 4; ++ni)
#pragma unroll
    for (int reg = 0; reg < 4; ++reg)
      xcT[(ni * 16 + lc) * 132 + 16 * wv + quad * 4 + reg] = f2bf(acc[ni][reg]);
  __syncthreads();
  u16* XCT = (u16*)(ws + OFF_XCT);
  for (int i = tid; i < 8192; i += 512) {
    const int d = i >> 7, r = i & 127;
    const unsigned int row = (unsigned int)(base + r);
    const unsigned int bt = row / 325u;
    const unsigned int n = row - bt * 325u;
    XCT[(size_t)bt * 22528 + (size_t)d * 352 + n] = xcT[d * 132 + r];
  }
}

// =======  K3: spatial branch per bt — MFMA DFT + MFMA projection + softmax  =======
__global__ __launch_bounds__(256) void k_spatial3(const float* __restrict__ x,
                                                  float* __restrict__ ws) {
  __shared__ __align__(16) float smem[10240];   // 40,960 B
  const int tid = threadIdx.x;
  const int bt = blockIdx.x;
  const int lane = tid & 63, wv = tid >> 6;
  const int lc = lane & 15, quad = lane >> 4;

  // ---------------- Phase A: DFT GEMM (double-buffered x-tile) ----------------
  u16* Bt = (u16*)smem;                 // [2][64 e][40 k]  2 x 5120 B
  u16* xfl2 = (u16*)smem + 5120;        // [2 chunk][64 m][40]  5120 B
  const u16* TB = (const u16*)(ws + OFF_TB);
  const u16* WSPBu = (const u16*)(ws + OFF_WSPB);
  const float* xb = x + (size_t)bt * 20800;
  const int br = tid & 31, be0 = (tid >> 5) * 8;

  auto stageB = [&](int kc, u16* dst) {
    const int k0 = kc * 32;
    float v[8];
    if (k0 + br < 325) {
      const float* src = xb + (size_t)(k0 + br) * 64 + be0;
      *(float4*)v = *(const float4*)src;
      *(float4*)(v + 4) = *(const float4*)(src + 4);
    } else {
#pragma unroll
      for (int u = 0; u < 8; ++u) v[u] = 0.f;
    }
#pragma unroll
    for (int u = 0; u < 8; ++u) dst[(be0 + u) * 40 + br] = f2bf(v[u]);
  };

  floatx4 accA[4] = {};
  stageB(0, Bt);
  __syncthreads();
  for (int kc = 0; kc < 11; ++kc) {
    u16* cur = Bt + (kc & 1) * 2560;
    if (kc < 10) stageB(kc + 1, Bt + ((kc + 1) & 1) * 2560);
    const short8 af = *(const short8*)&TB[(size_t)(16 * wv + lc) * 352 + kc * 32 + quad * 8];
#pragma unroll
    for (int t = 0; t < 4; ++t) {
      const short8 bf_ = *(const short8*)&cur[(t * 16 + lc) * 40 + quad * 8];
      accA[t] = __builtin_amdgcn_mfma_f32_16x16x32_bf16(af, bf_, accA[t], 0, 0, 0);
    }
    __syncthreads();
  }

  // xf staged CHUNKED by 32-e halves, stride-40 rows (no row aliasing)
#pragma unroll
  for (int t = 0; t < 4; ++t)
#pragma unroll
    for (int r = 0; r < 4; ++r)
      xfl2[(t >> 1) * 2560 + (16 * wv + quad * 4 + r) * 40 + (t & 1) * 16 + lc] =
          f2bf(accA[t][r]);
  __syncthreads();

  // ---------------- Phase B: projection GEMM (W frags from global) ----------------
  floatx4 acc2[12] = {};
#pragma unroll
  for (int kc2 = 0; kc2 < 2; ++kc2) {
    const short8 af2 = *(const short8*)&xfl2[kc2 * 2560 + (16 * wv + lc) * 40 + quad * 8];
#pragma unroll
    for (int t = 0; t < 12; ++t) {
      const short8 bf2 = *(const short8*)&WSPBu[(t * 16 + lc) * 64 + kc2 * 32 + quad * 8];
      acc2[t] = __builtin_amdgcn_mfma_f32_16x16x32_bf16(af2, bf2, acc2[t], 0, 0, 0);
    }
  }
  __syncthreads();

  // ---------------- Phase C ----------------
  float* sq_q = smem;             // [32][64]
  float* sq_k = smem + 2048;      // [32][64] -> absk*SCALE/||k||
  float* vfre = smem + 4096;
  float* vfim = smem + 6144;
  float* wbar = smem + 8192;
  for (int i = tid; i < 2048; i += 256) wbar[i] = 0.f;
  {
    const int fb = 8 * wv + ((quad >= 2) ? 4 : 0);
    const int isim = quad & 1;
#pragma unroll
    for (int t = 0; t < 12; ++t) {
      const int mat = t >> 2;
      const int d = (t & 3) * 16 + lc;
#pragma unroll
      for (int r = 0; r < 4; ++r) {
        const float v = acc2[t][r];
        if (mat == 2) {
          if (isim) vfim[(fb + r) * 64 + d] = v;
          else vfre[(fb + r) * 64 + d] = v;
        } else {
          const float s2 = v * v + __shfl_xor(v * v, 16);
          if (!isim) {
            if (mat == 0) sq_q[(fb + r) * 64 + d] = s2;
            else sq_k[(fb + r) * 64 + d] = s2;
          }
        }
      }
    }
  }
  __syncthreads();
  const float inv_nq = rsqrtf(ws[OFF_NORM + 0]);
  const float inv_nk = rsqrtf(ws[OFF_NORM + 1]);
  for (int i = tid; i < 2048; i += 256)
    sq_k[i] = 0.25f * inv_nk * sqrtf(sq_k[i]);
  __syncthreads();
  {
    const int d = tid & 63, fb2 = tid >> 6, hd = d & 15;
    const float* wqa = ws + OFF_WQA;
    float wacc[32];
#pragma unroll
    for (int j = 0; j < 32; ++j) wacc[j] = 0.f;
    for (int r8 = 0; r8 < 8; ++r8) {
      const int m = fb2 + (r8 << 2);
      const float aq = inv_nq * sqrtf(sq_q[m * 64 + d]);
      float sv[32];
      float mx = -1e30f;
#pragma unroll
      for (int j = 0; j < 32; ++j) {
        const float a = (j == 0) ? aq : wqa[(m * 31 + (j - 1)) * 16 + hd];
        const float s = sq_k[j * 64 + d] * a;
        sv[j] = s;
        mx = fmaxf(mx, s);
      }
      float sum = 0.f;
#pragma unroll
      for (int j = 0; j < 32; ++j) {
        const float ev = __expf(sv[j] - mx);
        sv[j] = ev;
        sum += ev;
      }
      const float sc = 0.03125f / sum;
#pragma unroll
      for (int j = 0; j < 32; ++j) wacc[j] += sv[j] * sc;
    }
#pragma unroll
    for (int j = 0; j < 32; ++j) atomicAdd(&wbar[j * 64 + d], wacc[j]);
  }
  __syncthreads();
  // OFT[bt][d][2j|2j+1] packed bf16, coalesced uint writes
  unsigned int* OFTu = (unsigned int*)(ws + OFF_OFT) + (size_t)bt * 2048;
  for (int i2 = tid; i2 < 2048; i2 += 256) {
    const int d = i2 >> 5, j = i2 & 31;
    const float w = wbar[j * 64 + d];
    const unsigned int lo = f2bf(vfre[j * 64 + d] * w);
    const unsigned int hi = f2bf(vfim[j * 64 + d] * w);
    OFTu[i2] = lo | (hi << 16);
  }
}

// =======  K5: alt[b,n',d] = sum_s (-1)^s vt[b, n'*12+s, d]  =======
__global__ __launch_bounds__(256) void k_alt(float* __restrict__ ws) {
  const int idx = blockIdx.x * 256 + threadIdx.x;
  if (idx >= 32 * 325 * 64) return;
  const int dd = idx & 63;
  const int n = (idx >> 6) % 325;
  const int b = idx / (64 * 325);
  const float* vt = ws + OFF_VT + ((size_t)b * 3900 + (size_t)n * 12) * 64 + dd;
  float s = 0.f, sign = 1.f;
  for (int k = 0; k < 12; ++k) {
    s += sign * vt[k * 64];
    sign = -sign;
  }
  ws[OFF_ALT + idx] = s;
}

// =======  K6 (R8): barrier-free MFMA — C = AN@XCT + T2@OFT, + temporal + bias  =======
// All operands bf16 fragment-ready in ws; no LDS, no __syncthreads in main loop.
__global__ __launch_bounds__(256) void k_final2(const float* __restrict__ bmlp,
                                                float* __restrict__ ws,
                                                float* __restrict__ out) {
  const int tid = threadIdx.x;
  const int bt = blockIdx.x / 3, mc = blockIdx.x % 3;
  const int m0 = mc * 128;
  const int wave = tid >> 6, lane = tid & 63;
  const int quad = lane >> 4, lc = lane & 15;

  const u16* ANB = (const u16*)(ws + OFF_ANB);
  const u16* T2B = (const u16*)(ws + OFF_T2);
  const u16* XCT = (const u16*)(ws + OFF_XCT) + (size_t)bt * 22528;
  const u16* OFT = (const u16*)(ws + OFF_OFT) + (size_t)bt * 4096;

  floatx4 acc[2][4] = {};

#pragma unroll
  for (int c13 = 0; c13 < 13; ++c13) {
    const bool gcn = (c13 < 11);
    const u16* Asrc = gcn ? ANB : T2B;
    const int astr = gcn ? 352 : 64;
    const int acol = gcn ? c13 * 32 : (c13 - 11) * 32;
    const u16* Bsrc = gcn ? XCT : OFT;
    const int bstr = gcn ? 352 : 64;
    short8 af[2], bf_[4];
#pragma unroll
    for (int mi = 0; mi < 2; ++mi) {
      const int gr = m0 + wave * 32 + mi * 16 + lc;
      short8 a = {};
      if (gr < 325)
        a = *(const short8*)&Asrc[(size_t)gr * astr + acol + quad * 8];
      af[mi] = a;
    }
#pragma unroll
    for (int ni = 0; ni < 4; ++ni)
      bf_[ni] = *(const short8*)&Bsrc[(size_t)(ni * 16 + lc) * bstr + acol + quad * 8];
#pragma unroll
    for (int mi = 0; mi < 2; ++mi)
#pragma unroll
      for (int ni = 0; ni < 4; ++ni)
        acc[mi][ni] = __builtin_amdgcn_mfma_f32_16x16x32_bf16(
            af[mi], bf_[ni], acc[mi][ni], 0, 0, 0);
  }

  const int b = bt / 12, t = bt - b * 12;
  const float sgn = (t & 1) ? -1.f : 1.f;
#pragma unroll
  for (int ni = 0; ni < 4; ++ni) {
    const int d = ni * 16 + lc;
    const float bias = bmlp[d];
#pragma unroll
    for (int mi = 0; mi < 2; ++mi) {
#pragma unroll
      for (int reg = 0; reg < 4; ++reg) {
        const int n = m0 + wave * 32 + mi * 16 + quad * 4 + reg;
        if (n >= 325) continue;
        const float v = ws[OFF_VT + ((size_t)b * 3900 + (size_t)n * 12 + t) * 64 + d];
        const float al = ws[OFF_ALT + ((size_t)b * 325 + n) * 64 + d];
        const float te = (v - sgn * al * (1.f / 12.f)) * (1.f / 6.f);
        out[((size_t)bt * 325 + n) * 64 + d] = acc[mi][ni][reg] + bias + te;
      }
    }
  }
}

extern "C" void kernel_launch(void* const* d_in, const int* in_sizes, int n_in,
                              void* d_out, int out_size, void* d_ws, size_t ws_size,
                              hipStream_t stream) {
  const float* x = (const float*)d_in[0];
  const float* adj = (const float*)d_in[1];
  const float* Wq_g = (const float*)d_in[2];
  const float* Wk_g = (const float*)d_in[3];
  const float* Wv_g = (const float*)d_in[4];
  // d_in[5], d_in[6] (Wq_t, Wk_t), d_in[12] (weights_Q_t), d_in[14] (t_modes):
  // dead code — temporal softmax axis == mean axis => out = vf/6.
  const float* Wv_t = (const float*)d_in[7];
  const float* Wfc1 = (const float*)d_in[8];
  const float* Wmlp = (const float*)d_in[9];
  const float* bmlp = (const float*)d_in[10];
  const float* wQ = (const float*)d_in[11];
  const int* sp_modes = (const int*)d_in[13];
  float* ws = (float*)d_ws;
  float* out = (float*)d_out;

  (void)in_sizes; (void)n_in; (void)out_size; (void)ws_size;

  hipMemsetAsync(ws + OFF_NORM, 0, 2 * sizeof(float), stream);
  k_prep<<<464, 256, 0, stream>>>(adj, Wmlp, Wfc1, wQ, Wv_t, Wq_g, Wk_g, Wv_g,
                                  sp_modes, ws);
  k_linear2<<<975, 512, 0, stream>>>(x, ws);
  k_spatial3<<<384, 256, 0, stream>>>(x, ws);
  k_alt<<<2600, 256, 0, stream>>>(ws);
  k_final2<<<1152, 256, 0, stream>>>(bmlp, ws, out);
}